// Round 14
// baseline (728.816 us; speedup 1.0000x reference)
//
#include <hip/hip_runtime.h>
#include <math.h>

#define Hd 128
#define Ln 64
#define Bsz 8
#define NTHR 512
#define NBLK 512   // 64 column-blocks per batch x 8 batches

// d_ws: T[8][64][64][128] f32 (16MB) + flags int[8][64][64] (128KB).
// COLUMN-OWNERSHIP: block (b,p) owns column jj=63-p, walks i=1..p.
// Deps of (i,jj): left col = SELF; right anti-diagonal rows k>=1 are covered by
// STALE flag (i-2, jj+2) (2 hops old, no real spin); ONLY k=0 needs the fresh
// flag (i-1, jj+1). Post-flag tail = 1 fresh row + chunk-0 MFMA + merge.
// Matvec on MFMA, exact 3-way bf16 split; Wrep B-frags in registers.
// Rows >= i hard-masked (t=0) -> stale/uninit LDS can never leak (NaN-safe).

typedef __attribute__((ext_vector_type(8))) short short8v;
typedef __attribute__((ext_vector_type(4))) float f32x4;

__global__ void init_kernel(const float* __restrict__ wf, float* __restrict__ T,
                            int* __restrict__ flg) {
    int idx = blockIdx.x * 256 + threadIdx.x;   // 0..65535
    int b = idx >> 13;
    int rest = idx & 8191;
    T[(size_t)b * (Ln * Ln * Hd) + rest] = wf[idx];
    if (idx < Bsz * Ln * Ln) flg[idx] = 0;
}

__device__ __forceinline__ float2 ld_row8(const float* p) {
    unsigned long long v = __hip_atomic_load((const unsigned long long*)p,
                                             __ATOMIC_RELAXED, __HIP_MEMORY_SCOPE_AGENT);
    return __builtin_bit_cast(float2, v);
}

__device__ __forceinline__ void wait_flag(const int* p) {
    while (__hip_atomic_load(p, __ATOMIC_RELAXED, __HIP_MEMORY_SCOPE_AGENT) == 0)
        __builtin_amdgcn_s_sleep(1);
    asm volatile("" ::: "memory");
}

// exact 3-way bf16 decomposition: x == bf(a0)+bf(a1)+bf(a2)
__device__ __forceinline__ void bf_split3(float x, unsigned short& a0,
                                          unsigned short& a1, unsigned short& a2) {
    unsigned u0 = __builtin_bit_cast(unsigned, x);
    a0 = (unsigned short)(u0 >> 16);
    float f0 = __builtin_bit_cast(float, u0 & 0xffff0000u);
    float r1 = x - f0;
    unsigned u1 = __builtin_bit_cast(unsigned, r1);
    a1 = (unsigned short)(u1 >> 16);
    float f1 = __builtin_bit_cast(float, u1 & 0xffff0000u);
    float r2 = r1 - f1;
    a2 = (unsigned short)(__builtin_bit_cast(unsigned, r2) >> 16);
}

__device__ __forceinline__ float bfval(unsigned short v) {
    return __builtin_bit_cast(float, ((unsigned)v) << 16);
}

#define KSTEP(SK, B0_, B1_, B2_)                                                \
    {                                                                           \
        int off = ((16 * ch + (ln & 15)) << 7) +                                \
                  ((((SK << 2) + (ln >> 4)) ^ (ln & 15)) << 3);                 \
        short8v a0 = *(const short8v*)&sH0[off];                                \
        short8v a1 = *(const short8v*)&sH1[off];                                \
        short8v a2 = *(const short8v*)&sH2[off];                                \
        acc = __builtin_amdgcn_mfma_f32_16x16x32_bf16(a0, B0_, acc, 0, 0, 0);   \
        acc = __builtin_amdgcn_mfma_f32_16x16x32_bf16(a0, B1_, acc, 0, 0, 0);   \
        acc = __builtin_amdgcn_mfma_f32_16x16x32_bf16(a1, B0_, acc, 0, 0, 0);   \
        acc = __builtin_amdgcn_mfma_f32_16x16x32_bf16(a0, B2_, acc, 0, 0, 0);   \
        acc = __builtin_amdgcn_mfma_f32_16x16x32_bf16(a1, B1_, acc, 0, 0, 0);   \
        acc = __builtin_amdgcn_mfma_f32_16x16x32_bf16(a2, B0_, acc, 0, 0, 0);   \
    }

// h_hat for one row from L,R registers; write LDS row k (swizzled)
__device__ __forceinline__ void row_hhat(
    float2 L, float2 R, float pl, float pr, int k, int ln,
    unsigned short* __restrict__ sH0, unsigned short* __restrict__ sH1,
    unsigned short* __restrict__ sH2,
    float bl, float br)
{
    float sl = pl + bl, sr2 = pr + br;
    float mm = fmaxf(sl, sr2);
    float e0 = __expf(sl - mm), e1 = __expf(sr2 - mm);
    float inv = 1.f / (e0 + e1);
    float w0 = e0 * inv, w1 = e1 * inv;
    float h0 = w0 * L.x + w1 * R.x;
    float h1 = w0 * L.y + w1 * R.y;
    unsigned short x0, x1, x2, y0, y1, y2;
    bf_split3(h0, x0, x1, x2);
    bf_split3(h1, y0, y1, y2);
    int off = (k << 7) + (((ln >> 2) ^ (k & 15)) << 3) + ((2 * ln) & 7);
    *(unsigned*)&sH0[off] = (unsigned)x0 | ((unsigned)y0 << 16);
    *(unsigned*)&sH1[off] = (unsigned)x1 | ((unsigned)y1 << 16);
    *(unsigned*)&sH2[off] = (unsigned)x2 | ((unsigned)y2 << 16);
}

template<int NCH>
__device__ __forceinline__ void do_cell(
    int i, int jj, int b, int wv, int ln, int tid,
    const float* __restrict__ Tb, float* __restrict__ T, float* __restrict__ out,
    int* __restrict__ flgb,
    unsigned short* __restrict__ sH0, unsigned short* __restrict__ sH1,
    unsigned short* __restrict__ sH2,
    float (*part)[Ln], float* __restrict__ tmpS,
    const short8v (&B0)[4], const short8v (&B1)[4], const short8v (&B2)[4],
    float2 wlv, float2 wrv, float bl, float br, float bs, float wsc, float bbc)
{
    const int colc = 16 * wv + (ln & 15);

    // ================= PRE-FLAG phase =================
    if (i >= 2) {
        // stale flag (2 hops old): covers k=1 row (itself) + k>=2 anti-diagonal
        if (i >= 3) wait_flag(&flgb[(i - 2) * Ln + jj + 2]);
        float2 Lr[8], Rr[8];
        #pragma unroll
        for (int r = 0; r < 8; ++r) {
            int k = wv + 8 * r;
            int kcl = k < 1 ? 1 : (k > i - 1 ? i - 1 : k);
            Lr[r] = ld_row8(Tb + ((size_t)kcl * Ln + jj) * Hd + 2 * ln);
            Rr[r] = ld_row8(Tb + ((size_t)(i - 1 - kcl) * Ln + (jj + kcl + 1)) * Hd + 2 * ln);
        }
        float pl[8], pr[8];
        #pragma unroll
        for (int r = 0; r < 8; ++r) {
            pl[r] = Lr[r].x * wlv.x + Lr[r].y * wlv.y;
            pr[r] = Rr[r].x * wrv.x + Rr[r].y * wrv.y;
        }
        #pragma unroll
        for (int off2 = 32; off2 > 0; off2 >>= 1) {
            #pragma unroll
            for (int r = 0; r < 8; ++r) {
                pl[r] += __shfl_xor(pl[r], off2);
                pr[r] += __shfl_xor(pr[r], off2);
            }
        }
        #pragma unroll
        for (int r = 0; r < 8; ++r) {
            int k = wv + 8 * r;
            if (k != 0)   // row 0 is the fresh row, written post-flag
                row_hhat(Lr[r], Rr[r], pl[r], pr[r], k, ln, sH0, sH1, sH2, bl, br);
        }
    }
    __syncthreads();   // B1: rows 1..63 visible

    // chunks 1..NCH-1 (rows 16..): MFMA + tmpS + partial logits (pre-flag)
    #pragma unroll
    for (int ch = 1; ch < NCH; ++ch) {
        f32x4 acc = {0.f, 0.f, 0.f, 0.f};
        KSTEP(0, B0[0], B1[0], B2[0])
        KSTEP(1, B0[1], B1[1], B2[1])
        KSTEP(2, B0[2], B1[2], B2[2])
        KSTEP(3, B0[3], B1[3], B2[3])
        float p[4];
        #pragma unroll
        for (int q = 0; q < 4; ++q) {
            int row = 16 * ch + (ln >> 4) * 4 + q;
            int offh = (row << 7) + (((colc >> 3) ^ (row & 15)) << 3) + (colc & 7);
            float h = (bfval(sH0[offh]) + bfval(sH1[offh])) + bfval(sH2[offh]);
            float t = fmaxf(acc[q] + bbc, 0.f) + h;
            t = (row < i) ? t : 0.f;                 // hard mask (NaN-safe)
            tmpS[(row - 16) * 132 + colc] = t;
            p[q] = t * wsc;
        }
        #pragma unroll
        for (int off2 = 1; off2 <= 8; off2 <<= 1) {
            #pragma unroll
            for (int q = 0; q < 4; ++q) p[q] += __shfl_xor(p[q], off2);
        }
        if ((ln & 15) == 0) {
            #pragma unroll
            for (int q = 0; q < 4; ++q)
                part[wv][16 * ch + (ln >> 4) * 4 + q] = p[q];
        }
    }

    // ================= POST-FLAG tail =================
    if (wv == 0) {
        if (i >= 2) wait_flag(&flgb[(i - 1) * Ln + jj + 1]);   // THE handoff
        // fresh row k=0: left = leaf T[0][jj], right = T[i-1][jj+1]
        float2 L = ld_row8(Tb + (size_t)jj * Hd + 2 * ln);
        float2 R = ld_row8(Tb + ((size_t)(i - 1) * Ln + (jj + 1)) * Hd + 2 * ln);
        float pl = L.x * wlv.x + L.y * wlv.y;
        float pr = R.x * wrv.x + R.y * wrv.y;
        #pragma unroll
        for (int off2 = 32; off2 > 0; off2 >>= 1) {
            pl += __shfl_xor(pl, off2);
            pr += __shfl_xor(pr, off2);
        }
        row_hhat(L, R, pl, pr, 0, ln, sH0, sH1, sH2, bl, br);
    }
    __syncthreads();   // B2: row 0 visible

    // chunk 0 (rows 0..15): MFMA + partial logits
    float tmp0[4];
    {
        const int ch = 0;
        f32x4 acc = {0.f, 0.f, 0.f, 0.f};
        KSTEP(0, B0[0], B1[0], B2[0])
        KSTEP(1, B0[1], B1[1], B2[1])
        KSTEP(2, B0[2], B1[2], B2[2])
        KSTEP(3, B0[3], B1[3], B2[3])
        float p[4];
        #pragma unroll
        for (int q = 0; q < 4; ++q) {
            int row = (ln >> 4) * 4 + q;
            int offh = (row << 7) + (((colc >> 3) ^ (row & 15)) << 3) + (colc & 7);
            float h = (bfval(sH0[offh]) + bfval(sH1[offh])) + bfval(sH2[offh]);
            float t = fmaxf(acc[q] + bbc, 0.f) + h;
            t = (row < i) ? t : 0.f;                 // hard mask
            tmp0[q] = t;
            p[q] = t * wsc;
        }
        #pragma unroll
        for (int off2 = 1; off2 <= 8; off2 <<= 1) {
            #pragma unroll
            for (int q = 0; q < 4; ++q) p[q] += __shfl_xor(p[q], off2);
        }
        if ((ln & 15) == 0) {
            #pragma unroll
            for (int q = 0; q < 4; ++q)
                part[wv][(ln >> 4) * 4 + q] = p[q];
        }
    }
    __syncthreads();   // B3: part complete

    // redundant all-wave softmax over k (no extra barrier)
    float lgv = -INFINITY;
    if (ln < i) {
        float ss = ((part[0][ln] + part[1][ln]) + (part[2][ln] + part[3][ln]))
                 + ((part[4][ln] + part[5][ln]) + (part[6][ln] + part[7][ln]));
        lgv = ss + bs;
    }
    float M = lgv;
    #pragma unroll
    for (int off2 = 32; off2 > 0; off2 >>= 1) M = fmaxf(M, __shfl_xor(M, off2));
    M = fmaxf(M, bs);
    float e = (ln < i) ? __expf(lgv - M) : 0.f;
    float S = e;
    #pragma unroll
    for (int off2 = 32; off2 > 0; off2 >>= 1) S += __shfl_xor(S, off2);
    float den = S + (float)(Ln - i) * __expf(bs - M);

    // weighted sum over k (chunk 0 from regs, chunks>=1 from tmpS)
    float v = 0.f;
    #pragma unroll
    for (int q = 0; q < 4; ++q) {
        int row = (ln >> 4) * 4 + q;
        v += __shfl(e, row) * tmp0[q];
    }
    #pragma unroll
    for (int ch = 1; ch < NCH; ++ch) {
        #pragma unroll
        for (int q = 0; q < 4; ++q) {
            int row = 16 * ch + (ln >> 4) * 4 + q;
            v += __shfl(e, row) * tmpS[(row - 16) * 132 + colc];
        }
    }
    v += __shfl_xor(v, 16);
    v += __shfl_xor(v, 32);
    if (ln < 16) {
        float res = v / den;
        __hip_atomic_store(&T[(((size_t)b * Ln + i) * Ln + jj) * Hd + colc], res,
                           __ATOMIC_RELAXED, __HIP_MEMORY_SCOPE_AGENT);
        if (i == Ln - 1) out[b * Hd + colc] = res;
    }
    __syncthreads();   // B4: per-wave vmcnt(0) drains all result stores
    if (tid == 0)
        __hip_atomic_store(&flgb[i * Ln + jj], 1, __ATOMIC_RELAXED,
                           __HIP_MEMORY_SCOPE_AGENT);
}

__global__ __launch_bounds__(NTHR, 2)
void glt_df(const float* __restrict__ Wl, const float* __restrict__ blp,
            const float* __restrict__ Wr, const float* __restrict__ brp,
            const float* __restrict__ Wrep, const float* __restrict__ brepp,
            const float* __restrict__ Wsv, const float* __restrict__ bsp,
            float* __restrict__ T, int* __restrict__ flg, float* __restrict__ out)
{
    __shared__ __align__(16) unsigned short sH0[Ln * Hd];   // 16 KB
    __shared__ __align__(16) unsigned short sH1[Ln * Hd];   // 16 KB
    __shared__ __align__(16) unsigned short sH2[Ln * Hd];   // 16 KB
    __shared__ __align__(16) float tmpS[48 * 132];          // 25.3 KB (rows 16..63)
    __shared__ float part[8][Ln];                           // 2 KB

    const int tid = threadIdx.x;
    const int wv  = tid >> 6;
    const int ln  = tid & 63;
    const int b   = blockIdx.x & 7;      // XCD round-robin: batch -> XCD
    const int p   = blockIdx.x >> 3;     // 0..63
    const int jj  = 63 - p;              // owned column; deps at LOWER blockIdx

    if (p == 0) return;                  // column 63 has no cells

    // ---- B-fragments: Wrep cols [16wv,16wv+16) exact 3-way bf16, registers ----
    const int bcol = 16 * wv + (ln & 15);
    short8v B0[4], B1[4], B2[4];
    #pragma unroll
    for (int sk = 0; sk < 4; ++sk) {
        #pragma unroll
        for (int jx = 0; jx < 8; ++jx) {
            int k = 32 * sk + (ln >> 4) * 8 + jx;
            float w = Wrep[k * Hd + bcol];
            unsigned short w0, w1, w2;
            bf_split3(w, w0, w1, w2);
            B0[sk][jx] = (short)w0;
            B1[sk][jx] = (short)w1;
            B2[sk][jx] = (short)w2;
        }
    }

    const float bl = blp[0], br = brp[0], bs = bsp[0];
    const float2 wlv = *(const float2*)&Wl[2 * ln];
    const float2 wrv = *(const float2*)&Wr[2 * ln];
    const float wsc = Wsv[bcol];
    const float bbc = brepp[bcol];

    const float* Tb = T + (size_t)b * (Ln * Ln * Hd);
    int* flgb = flg + b * (Ln * Ln);

    // ---- column walk: cells (i, jj) for i = 1..p ----
    for (int i = 1; i <= p; ++i) {
        switch ((i + 15) >> 4) {
            case 1: do_cell<1>(i, jj, b, wv, ln, tid, Tb, T, out, flgb,
                               sH0, sH1, sH2, part, tmpS, B0, B1, B2,
                               wlv, wrv, bl, br, bs, wsc, bbc); break;
            case 2: do_cell<2>(i, jj, b, wv, ln, tid, Tb, T, out, flgb,
                               sH0, sH1, sH2, part, tmpS, B0, B1, B2,
                               wlv, wrv, bl, br, bs, wsc, bbc); break;
            case 3: do_cell<3>(i, jj, b, wv, ln, tid, Tb, T, out, flgb,
                               sH0, sH1, sH2, part, tmpS, B0, B1, B2,
                               wlv, wrv, bl, br, bs, wsc, bbc); break;
            default: do_cell<4>(i, jj, b, wv, ln, tid, Tb, T, out, flgb,
                                sH0, sH1, sH2, part, tmpS, B0, B1, B2,
                                wlv, wrv, bl, br, bs, wsc, bbc); break;
        }
    }
}

extern "C" void kernel_launch(void* const* d_in, const int* in_sizes, int n_in,
                              void* d_out, int out_size, void* d_ws, size_t ws_size,
                              hipStream_t stream)
{
    const float* wf   = (const float*)d_in[0];
    const float* Wl   = (const float*)d_in[2];
    const float* bl   = (const float*)d_in[3];
    const float* Wr   = (const float*)d_in[4];
    const float* br   = (const float*)d_in[5];
    const float* Wrep = (const float*)d_in[6];
    const float* brep = (const float*)d_in[7];
    const float* Ws   = (const float*)d_in[8];
    const float* bs   = (const float*)d_in[9];

    float* T   = (float*)d_ws;                                   // 16 MB
    int*   flg = (int*)((char*)d_ws + (size_t)Bsz * Ln * Ln * Hd * 4);
    float* out = (float*)d_out;

    init_kernel<<<256, 256, 0, stream>>>(wf, T, flg);
    glt_df<<<NBLK, NTHR, 0, stream>>>(Wl, bl, Wr, br, Wrep, brep, Ws, bs,
                                      T, flg, out);
}

// Round 16
// 487.016 us; speedup vs baseline: 1.4965x; 1.4965x over previous
//
#include <hip/hip_runtime.h>
#include <math.h>

#define Hd 128
#define Ln 64
#define Bsz 8
#define NBLK 256
#define NTHR 512
#define SLOTS 32   // blocks per batch (r8-proven envelope; 256 blocks = 1/CU, always resident)

// d_ws: T[8][64][64][128] f32 (16MB) + flags int[8][64][64] (128KB).
// Deps of cell (i,j): flags (i-1,j) and (i-1,j+1) (transitive cover).
// r8 cell + (a) phase-A truncation (only rows k < 16*NCH exist for the MFMA),
// (b) redundant all-wave k-softmax (3 barriers/cell, no sER roundtrip).
// Matvec on MFMA with EXACT 3-way bf16 split; Wrep B-frags in registers.
// NOTE: 512-block flag-dataflow deadlocks under partial residency (r15);
// 256 blocks on 256 CUs is the safe envelope.

typedef __attribute__((ext_vector_type(8))) short short8v;
typedef __attribute__((ext_vector_type(4))) float f32x4;

__global__ void init_kernel(const float* __restrict__ wf, float* __restrict__ T,
                            int* __restrict__ flg) {
    int idx = blockIdx.x * 256 + threadIdx.x;   // 0..65535
    int b = idx >> 13;
    int rest = idx & 8191;
    T[(size_t)b * (Ln * Ln * Hd) + rest] = wf[idx];
    if (idx < Bsz * Ln * Ln) flg[idx] = 0;
}

__device__ __forceinline__ float2 ld_row8(const float* p) {
    unsigned long long v = __hip_atomic_load((const unsigned long long*)p,
                                             __ATOMIC_RELAXED, __HIP_MEMORY_SCOPE_AGENT);
    return __builtin_bit_cast(float2, v);
}

__device__ __forceinline__ void wait_flag(const int* p) {
    while (__hip_atomic_load(p, __ATOMIC_RELAXED, __HIP_MEMORY_SCOPE_AGENT) == 0)
        __builtin_amdgcn_s_sleep(1);
    asm volatile("" ::: "memory");
}

// exact 3-way bf16 decomposition: x == bf(a0)+bf(a1)+bf(a2)
__device__ __forceinline__ void bf_split3(float x, unsigned short& a0,
                                          unsigned short& a1, unsigned short& a2) {
    unsigned u0 = __builtin_bit_cast(unsigned, x);
    a0 = (unsigned short)(u0 >> 16);
    float f0 = __builtin_bit_cast(float, u0 & 0xffff0000u);
    float r1 = x - f0;
    unsigned u1 = __builtin_bit_cast(unsigned, r1);
    a1 = (unsigned short)(u1 >> 16);
    float f1 = __builtin_bit_cast(float, u1 & 0xffff0000u);
    float r2 = r1 - f1;
    a2 = (unsigned short)(__builtin_bit_cast(unsigned, r2) >> 16);
}

__device__ __forceinline__ float bfval(unsigned short v) {
    return __builtin_bit_cast(float, ((unsigned)v) << 16);
}

#define KSTEP(SK, B0_, B1_, B2_)                                                \
    {                                                                           \
        int off = ((16 * ch + (ln & 15)) << 7) +                                \
                  ((((SK << 2) + (ln >> 4)) ^ (ln & 15)) << 3);                 \
        short8v a0 = *(const short8v*)&sH0[off];                                \
        short8v a1 = *(const short8v*)&sH1[off];                                \
        short8v a2 = *(const short8v*)&sH2[off];                                \
        acc = __builtin_amdgcn_mfma_f32_16x16x32_bf16(a0, B0_, acc, 0, 0, 0);   \
        acc = __builtin_amdgcn_mfma_f32_16x16x32_bf16(a0, B1_, acc, 0, 0, 0);   \
        acc = __builtin_amdgcn_mfma_f32_16x16x32_bf16(a1, B0_, acc, 0, 0, 0);   \
        acc = __builtin_amdgcn_mfma_f32_16x16x32_bf16(a0, B2_, acc, 0, 0, 0);   \
        acc = __builtin_amdgcn_mfma_f32_16x16x32_bf16(a1, B1_, acc, 0, 0, 0);   \
        acc = __builtin_amdgcn_mfma_f32_16x16x32_bf16(a2, B0_, acc, 0, 0, 0);   \
    }

template<int NCH>
__device__ __forceinline__ void do_cell(
    int i, int jj, int b, int wv, int ln, int tid,
    const float* __restrict__ Tb, float* __restrict__ T, float* __restrict__ out,
    int* __restrict__ flgb,
    unsigned short* __restrict__ sH0, unsigned short* __restrict__ sH1,
    unsigned short* __restrict__ sH2,
    float (*part)[Ln],
    const short8v (&B0)[4], const short8v (&B1)[4], const short8v (&B2)[4],
    float2 wlv, float2 wrv, float bl, float br, float bs, float wsc, float bbc)
{
    constexpr int NR = 2 * NCH;   // phase-A rows/wave: covers exactly k < 16*NCH

    // ---- wait for the two covering deps ----
    if (i >= 2) {
        wait_flag(&flgb[(i - 1) * Ln + jj]);
        wait_flag(&flgb[(i - 1) * Ln + jj + 1]);
    }

    // ---- phase A: rows k < 16*NCH (k>=i clamped duplicates; masked via e=0) ----
    float2 Lr[NR], Rr[NR];
    #pragma unroll
    for (int r = 0; r < NR; ++r) {
        int k = wv + 8 * r;
        int kcl = k < i ? k : i - 1;
        Lr[r] = ld_row8(Tb + ((size_t)kcl * Ln + jj) * Hd + 2 * ln);
        Rr[r] = ld_row8(Tb + ((size_t)(i - 1 - kcl) * Ln + (jj + kcl + 1)) * Hd + 2 * ln);
    }
    float pl[NR], pr[NR];
    #pragma unroll
    for (int r = 0; r < NR; ++r) {
        pl[r] = Lr[r].x * wlv.x + Lr[r].y * wlv.y;
        pr[r] = Rr[r].x * wrv.x + Rr[r].y * wrv.y;
    }
    #pragma unroll
    for (int off2 = 32; off2 > 0; off2 >>= 1) {
        #pragma unroll
        for (int r = 0; r < NR; ++r) {
            pl[r] += __shfl_xor(pl[r], off2);
            pr[r] += __shfl_xor(pr[r], off2);
        }
    }
    #pragma unroll
    for (int r = 0; r < NR; ++r) {
        int k = wv + 8 * r;
        float sl = pl[r] + bl, sr2 = pr[r] + br;
        float mm = fmaxf(sl, sr2);
        float e0 = __expf(sl - mm), e1 = __expf(sr2 - mm);
        float inv = 1.f / (e0 + e1);
        float w0 = e0 * inv, w1 = e1 * inv;
        float h0 = w0 * Lr[r].x + w1 * Rr[r].x;
        float h1 = w0 * Lr[r].y + w1 * Rr[r].y;
        unsigned short x0, x1, x2, y0, y1, y2;
        bf_split3(h0, x0, x1, x2);
        bf_split3(h1, y0, y1, y2);
        // cols 2ln,2ln+1 -> 16B-block (ln>>2) XOR-swizzled by row
        int off = (k << 7) + ((((ln >> 2)) ^ (k & 15)) << 3) + ((2 * ln) & 7);
        *(unsigned*)&sH0[off] = (unsigned)x0 | ((unsigned)y0 << 16);
        *(unsigned*)&sH1[off] = (unsigned)x1 | ((unsigned)y1 << 16);
        *(unsigned*)&sH2[off] = (unsigned)x2 | ((unsigned)y2 << 16);
    }
    __syncthreads();   // B1: rows 0..16*NCH-1 visible

    // ---- MFMA matvec: wave owns cols [16wv,16wv+16), chunks of 16 rows ----
    const int colc = 16 * wv + (ln & 15);
    float tmp[NCH][4];
    #pragma unroll
    for (int ch = 0; ch < NCH; ++ch) {
        f32x4 acc = {0.f, 0.f, 0.f, 0.f};
        KSTEP(0, B0[0], B1[0], B2[0])
        KSTEP(1, B0[1], B1[1], B2[1])
        KSTEP(2, B0[2], B1[2], B2[2])
        KSTEP(3, B0[3], B1[3], B2[3])
        float p[4];
        #pragma unroll
        for (int q = 0; q < 4; ++q) {
            int row = 16 * ch + (ln >> 4) * 4 + q;   // C/D: col=lane&15, row=(lane>>4)*4+reg
            int offh = (row << 7) + (((colc >> 3) ^ (row & 15)) << 3) + (colc & 7);
            float h = (bfval(sH0[offh]) + bfval(sH1[offh])) + bfval(sH2[offh]); // exact
            float t = fmaxf(acc[q] + bbc, 0.f) + h;
            tmp[ch][q] = t;
            p[q] = t * wsc;
        }
        #pragma unroll
        for (int off2 = 1; off2 <= 8; off2 <<= 1) {
            #pragma unroll
            for (int q = 0; q < 4; ++q) p[q] += __shfl_xor(p[q], off2);
        }
        if ((ln & 15) == 0) {
            #pragma unroll
            for (int q = 0; q < 4; ++q)
                part[wv][16 * ch + (ln >> 4) * 4 + q] = p[q];
        }
    }
    __syncthreads();   // B2: part complete

    // ---- redundant all-wave softmax over k (no extra barrier) ----
    float lgv = -INFINITY;
    if (ln < i) {
        float ss = ((part[0][ln] + part[1][ln]) + (part[2][ln] + part[3][ln]))
                 + ((part[4][ln] + part[5][ln]) + (part[6][ln] + part[7][ln]));
        lgv = ss + bs;
    }
    float M = lgv;
    #pragma unroll
    for (int off2 = 32; off2 > 0; off2 >>= 1) M = fmaxf(M, __shfl_xor(M, off2));
    M = fmaxf(M, bs);
    float e = (ln < i) ? __expf(lgv - M) : 0.f;
    float S = e;
    #pragma unroll
    for (int off2 = 32; off2 > 0; off2 >>= 1) S += __shfl_xor(S, off2);
    float den = S + (float)(Ln - i) * __expf(bs - M);

    // ---- weighted sum over k; store result row ----
    float v = 0.f;
    #pragma unroll
    for (int ch = 0; ch < NCH; ++ch) {
        #pragma unroll
        for (int q = 0; q < 4; ++q) {
            int row = 16 * ch + (ln >> 4) * 4 + q;
            v += __shfl(e, row) * tmp[ch][q];
        }
    }
    v += __shfl_xor(v, 16);
    v += __shfl_xor(v, 32);
    if (ln < 16) {
        float res = v / den;
        __hip_atomic_store(&T[(((size_t)b * Ln + i) * Ln + jj) * Hd + colc], res,
                           __ATOMIC_RELAXED, __HIP_MEMORY_SCOPE_AGENT);
        if (i == Ln - 1) out[b * Hd + colc] = res;
    }
    __syncthreads();   // B3: per-wave vmcnt(0) drains all result stores
    if (tid == 0)
        __hip_atomic_store(&flgb[i * Ln + jj], 1, __ATOMIC_RELAXED,
                           __HIP_MEMORY_SCOPE_AGENT);
}

__global__ __launch_bounds__(NTHR, 2)
void glt_df(const float* __restrict__ Wl, const float* __restrict__ blp,
            const float* __restrict__ Wr, const float* __restrict__ brp,
            const float* __restrict__ Wrep, const float* __restrict__ brepp,
            const float* __restrict__ Wsv, const float* __restrict__ bsp,
            float* __restrict__ T, int* __restrict__ flg, float* __restrict__ out)
{
    __shared__ __align__(16) unsigned short sH0[Ln * Hd];   // 16 KB
    __shared__ __align__(16) unsigned short sH1[Ln * Hd];   // 16 KB
    __shared__ __align__(16) unsigned short sH2[Ln * Hd];   // 16 KB
    __shared__ float part[8][Ln];                           // 2 KB

    const int tid = threadIdx.x;
    const int wv  = tid >> 6;
    const int ln  = tid & 63;
    const int b   = blockIdx.x & 7;      // XCD round-robin: batch -> XCD
    const int s   = blockIdx.x >> 3;     // slot 0..31 within batch

    // ---- B-fragments: Wrep cols [16wv,16wv+16) exact 3-way bf16, registers ----
    const int bcol = 16 * wv + (ln & 15);
    short8v B0[4], B1[4], B2[4];
    #pragma unroll
    for (int sk = 0; sk < 4; ++sk) {
        #pragma unroll
        for (int jx = 0; jx < 8; ++jx) {
            int k = 32 * sk + (ln >> 4) * 8 + jx;   // same k-map as A (consistent)
            float w = Wrep[k * Hd + bcol];
            unsigned short w0, w1, w2;
            bf_split3(w, w0, w1, w2);
            B0[sk][jx] = (short)w0;
            B1[sk][jx] = (short)w1;
            B2[sk][jx] = (short)w2;
        }
    }

    const float bl = blp[0], br = brp[0], bs = bsp[0];
    const float2 wlv = *(const float2*)&Wl[2 * ln];
    const float2 wrv = *(const float2*)&Wr[2 * ln];
    const float wsc = Wsv[bcol];
    const float bbc = brepp[bcol];

    const float* Tb = T + (size_t)b * (Ln * Ln * Hd);
    int* flgb = flg + b * (Ln * Ln);

    // ---- level-major walk: per-batch cell index c = s + 32t, t = 0..62 ----
    int i = 1, jj = s;
    while (jj >= Ln - i) { jj -= Ln - i; ++i; }
    for (int t = 0; t < 63; ++t) {
        switch ((i + 15) >> 4) {
            case 1: do_cell<1>(i, jj, b, wv, ln, tid, Tb, T, out, flgb,
                               sH0, sH1, sH2, part, B0, B1, B2,
                               wlv, wrv, bl, br, bs, wsc, bbc); break;
            case 2: do_cell<2>(i, jj, b, wv, ln, tid, Tb, T, out, flgb,
                               sH0, sH1, sH2, part, B0, B1, B2,
                               wlv, wrv, bl, br, bs, wsc, bbc); break;
            case 3: do_cell<3>(i, jj, b, wv, ln, tid, Tb, T, out, flgb,
                               sH0, sH1, sH2, part, B0, B1, B2,
                               wlv, wrv, bl, br, bs, wsc, bbc); break;
            default: do_cell<4>(i, jj, b, wv, ln, tid, Tb, T, out, flgb,
                                sH0, sH1, sH2, part, B0, B1, B2,
                                wlv, wrv, bl, br, bs, wsc, bbc); break;
        }
        if (t < 62) {
            jj += SLOTS;
            while (jj >= Ln - i) { jj -= Ln - i; ++i; }
        }
    }
}

extern "C" void kernel_launch(void* const* d_in, const int* in_sizes, int n_in,
                              void* d_out, int out_size, void* d_ws, size_t ws_size,
                              hipStream_t stream)
{
    const float* wf   = (const float*)d_in[0];
    const float* Wl   = (const float*)d_in[2];
    const float* bl   = (const float*)d_in[3];
    const float* Wr   = (const float*)d_in[4];
    const float* br   = (const float*)d_in[5];
    const float* Wrep = (const float*)d_in[6];
    const float* brep = (const float*)d_in[7];
    const float* Ws   = (const float*)d_in[8];
    const float* bs   = (const float*)d_in[9];

    float* T   = (float*)d_ws;                                   // 16 MB
    int*   flg = (int*)((char*)d_ws + (size_t)Bsz * Ln * Ln * Hd * 4);
    float* out = (float*)d_out;

    init_kernel<<<256, 256, 0, stream>>>(wf, T, flg);
    glt_df<<<NBLK, NTHR, 0, stream>>>(Wl, bl, Wr, br, Wrep, brep, Ws, bs,
                                      T, flg, out);
}